// Round 9
// baseline (590.326 us; speedup 1.0000x reference)
//
#include <hip/hip_runtime.h>

// CapsNet forward.
// conv1 (fp32 compute) -> x1t f16 [B][ih=20][iw=20][ci=16]  (ci innermost)
// packWB: w2 -> MFMA B-fragments; conv2: mfma_32x32x16_f16 -> u [B][144][8] f32
// packWr: W_route -> f16 c-pairs
// routing3: 1 sample/block, 256 thr; u_hat in 45 VGPRs/thread (no LDS u_hat);
//           LDS ~26 KB -> 4 blocks/CU. Deterministic spart reduction for s;
//           ds_add_f32 atomics for b-update.

typedef _Float16 half2_t __attribute__((ext_vector_type(2)));
typedef _Float16 f16x8 __attribute__((ext_vector_type(8)));
typedef float f32x16 __attribute__((ext_vector_type(16)));

static __device__ __forceinline__ float fdot2f(half2_t a, half2_t b, float c) {
#if __has_builtin(__builtin_amdgcn_fdot2)
  return __builtin_amdgcn_fdot2(a, b, c, false);
#else
  return c + (float)a[0] * (float)b[0] + (float)a[1] * (float)b[1];
#endif
}

static __device__ __forceinline__ half2_t h2(unsigned int u) {
  return __builtin_bit_cast(half2_t, u);
}

static __device__ __forceinline__ unsigned int pkh2(float a, float b) {
  half2_t h;
  h[0] = (_Float16)a;
  h[1] = (_Float16)b;
  return __builtin_bit_cast(unsigned int, h);
}

static __device__ __forceinline__ f32x16 zero16() {
  f32x16 z = {0.f, 0.f, 0.f, 0.f, 0.f, 0.f, 0.f, 0.f,
              0.f, 0.f, 0.f, 0.f, 0.f, 0.f, 0.f, 0.f};
  return z;
}

// w2[co][ci][kh][kw] f32 -> wBg[((kh*9+kw)*64 + lane)*8 + j] f16
__global__ __launch_bounds__(256) void packWB(
    const float* __restrict__ w2, _Float16* __restrict__ wBg) {
  int idx = blockIdx.x * 256 + threadIdx.x;
  if (idx >= 41472) return;
  int j = idx & 7;
  int lane = (idx >> 3) & 63;
  int step = idx >> 9;
  int kh = step / 9, kw = step - kh * 9;
  int co = lane & 31, ci = (lane >> 5) * 8 + j;
  wBg[idx] = (_Float16)w2[(co * 16 + ci) * 81 + kh * 9 + kw];
}

// W_route [144][10][16][8] f32 -> wPr [(i*10+o)*16+d][4] f16 c-pairs
__global__ __launch_bounds__(256) void packWr(
    const float* __restrict__ W, unsigned int* __restrict__ wPr) {
  int idx = blockIdx.x * 256 + threadIdx.x;   // 92160 dwords
  if (idx >= 92160) return;
  int cp = idx & 3;
  int row = idx >> 2;
  const float* src = W + (size_t)row * 8 + cp * 2;
  wPr[idx] = pkh2(src[0], src[1]);
}

__global__ __launch_bounds__(320) void conv1_kernel(
    const float* __restrict__ in, const float* __restrict__ w,
    const float* __restrict__ bias, _Float16* __restrict__ x1t) {
  __shared__ __align__(16) float sIn[784];      // 28x28
  __shared__ float sW[1296];                    // 16x81
  __shared__ __align__(16) _Float16 sOut[6400]; // [ih][iw][ci]
  int b = blockIdx.x, t = threadIdx.x;
  const float* inb = in + b * 784;
  for (int i = t; i < 784; i += 320) sIn[i] = inb[i];
  for (int i = t; i < 1296; i += 320) sW[i] = w[i];
  __syncthreads();
  int co = t / 20, oh = t % 20;   // 16*20 = 320 work items
  float bv = bias[co];
  float acc[20];
#pragma unroll
  for (int j = 0; j < 20; ++j) acc[j] = bv;
#pragma unroll
  for (int kh = 0; kh < 9; ++kh) {
    float r[28];
    const float4* row = (const float4*)&sIn[(oh + kh) * 28];
#pragma unroll
    for (int q = 0; q < 7; ++q) {
      float4 v = row[q];
      r[q * 4 + 0] = v.x; r[q * 4 + 1] = v.y; r[q * 4 + 2] = v.z; r[q * 4 + 3] = v.w;
    }
    const float* wr = &sW[co * 81 + kh * 9];
#pragma unroll
    for (int kw = 0; kw < 9; ++kw) {
      float wv = wr[kw];
#pragma unroll
      for (int j = 0; j < 20; ++j) acc[j] += wv * r[kw + j];
    }
  }
#pragma unroll
  for (int j = 0; j < 20; ++j) sOut[(oh * 20 + j) * 16 + co] = (_Float16)acc[j];
  __syncthreads();
  const unsigned int* s4 = (const unsigned int*)sOut;
  unsigned int* g4 = (unsigned int*)(x1t + (size_t)b * 6400);
  for (int i = t; i < 3200; i += 320) g4[i] = s4[i];
}

// conv2 MFMA: block = 8 samples (288 rows = 9 M-tiles of 32), 4 waves.
__global__ __launch_bounds__(256) void conv2_kernel(
    const _Float16* __restrict__ x1t, const _Float16* __restrict__ wBg,
    const float* __restrict__ bias, float* __restrict__ u) {
  __shared__ __align__(16) _Float16 sX[51200];  // 8 x [400][16]
  __shared__ __align__(16) _Float16 sB[4608];   // [kw 9][lane 64][8]
  int t = threadIdx.x;
  int bbase = blockIdx.x * 8;
  {
    const uint4* g = (const uint4*)(x1t + (size_t)bbase * 6400);
    uint4* s = (uint4*)sX;
#pragma unroll
    for (int i = 0; i < 25; ++i) s[t + i * 256] = g[t + i * 256];
  }
  int wv = t >> 6, lane = t & 63;
  int l31 = lane & 31, half = lane >> 5;
  int tbase0 = 0, tbase1 = 0, tbase2 = 0;
  {
    int r = wv * 32 + l31;
    int s = r / 36, pos = r - s * 36, oh = pos / 6, ow = pos - oh * 6;
    tbase0 = s * 6400 + (oh * 40 + ow * 2) * 16 + half * 8;
    r += 128;
    s = r / 36; pos = r - s * 36; oh = pos / 6; ow = pos - oh * 6;
    tbase1 = s * 6400 + (oh * 40 + ow * 2) * 16 + half * 8;
    if (wv == 0) {
      r = 256 + l31;
      s = r / 36; pos = r - s * 36; oh = pos / 6; ow = pos - oh * 6;
      tbase2 = s * 6400 + (oh * 40 + ow * 2) * 16 + half * 8;
    }
  }
  f32x16 acc0 = zero16(), acc1 = zero16(), acc2 = zero16();

  for (int kh = 0; kh < 9; ++kh) {
    __syncthreads();
    {
      const unsigned int* g = (const unsigned int*)(wBg + kh * 4608);
      unsigned int* s = (unsigned int*)sB;
#pragma unroll
      for (int i = 0; i < 9; ++i) s[t + i * 256] = g[t + i * 256];
    }
    __syncthreads();
    int abase = kh * 320;
#pragma unroll
    for (int kw = 0; kw < 9; ++kw) {
      f16x8 bf = *(const f16x8*)(sB + kw * 512 + lane * 8);
      f16x8 a0 = *(const f16x8*)(sX + tbase0 + abase + kw * 16);
      acc0 = __builtin_amdgcn_mfma_f32_32x32x16_f16(a0, bf, acc0, 0, 0, 0);
      f16x8 a1 = *(const f16x8*)(sX + tbase1 + abase + kw * 16);
      acc1 = __builtin_amdgcn_mfma_f32_32x32x16_f16(a1, bf, acc1, 0, 0, 0);
      if (wv == 0) {
        f16x8 a2 = *(const f16x8*)(sX + tbase2 + abase + kw * 16);
        acc2 = __builtin_amdgcn_mfma_f32_32x32x16_f16(a2, bf, acc2, 0, 0, 0);
      }
    }
  }
  float bv = bias[l31];
  int c8 = l31 >> 2;
  int ibco = (l31 & 3) * 36;
#pragma unroll
  for (int reg = 0; reg < 16; ++reg) {
    int rbase = (reg & 3) + 8 * (reg >> 2) + 4 * half;
    {
      int r = wv * 32 + rbase;
      int s = r / 36, pos = r - s * 36;
      u[(size_t)(bbase + s) * 1152 + (ibco + pos) * 8 + c8] = acc0[reg] + bv;
    }
    {
      int r = wv * 32 + 128 + rbase;
      int s = r / 36, pos = r - s * 36;
      u[(size_t)(bbase + s) * 1152 + (ibco + pos) * 8 + c8] = acc1[reg] + bv;
    }
    if (wv == 0) {
      int r = 256 + rbase;
      int s = r / 36, pos = r - s * 36;
      u[(size_t)(bbase + s) * 1152 + (ibco + pos) * 8 + c8] = acc2[reg] + bv;
    }
  }
}

// routing3: block = 1 sample, 256 threads. u_hat entirely in registers:
// thread t owns idx = e*256+t, e<45 (i = idx/80, dp = idx%80; dp cycles over
// exactly 5 values since 256 = 3*80+16). LDS ~26 KB -> 4 blocks/CU.
#define ADV(i, dp) { dp += 16; int ov = (dp >= 80) ? 1 : 0; dp -= ov * 80; i += 3 + ov; }
__global__ __launch_bounds__(256, 4) void routing3_kernel(
    const float* __restrict__ u, const unsigned int* __restrict__ wPr,
    float* __restrict__ out, int B) {
  __shared__ unsigned int ush[576];   // u f16 c-pairs [i][4]
  __shared__ float blog[1440];        // b [144][10] (atomically updated)
  __shared__ float cc[1440];          // c [144][10]
  __shared__ float spart[2720];       // [dp 80][j 17pad][2] partial s
  __shared__ float ss[160];           // s (dp*2+c ordering == [o][d])
  __shared__ float vv[160];           // v [10][16]
  __shared__ unsigned int vvh[80];    // v f16 d-pairs
  int b = blockIdx.x, t = threadIdx.x;
  const float* ub = u + (size_t)b * 1152;
  for (int j = t; j < 576; j += 256) {
    float2 p = *(const float2*)(ub + j * 2);
    ush[j] = pkh2(p.x, p.y);
  }
  for (int j = t; j < 1440; j += 256) blog[j] = 0.f;
  __syncthreads();

  // ---- u_hat into registers: uh[e] = f16 pair (d=2dd, 2dd+1) of (i, o) ----
  unsigned int uh[45];
  {
    const uint4* W4 = (const uint4*)wPr;   // rows [i*160 + o*16 + d] of 8 f16
    int i = t / 80, dp = t - (t / 80) * 80;
#pragma unroll
    for (int e = 0; e < 45; ++e) {
      int row = i * 160 + (dp >> 3) * 16 + (dp & 7) * 2;
      uint4 w0 = W4[row], w1 = W4[row + 1];
      const uint2* up = (const uint2*)&ush[i * 4];
      uint2 ua = up[0], ub2 = up[1];
      half2_t u0 = h2(ua.x), u1 = h2(ua.y), u2 = h2(ub2.x), u3 = h2(ub2.y);
      float a0 = fdot2f(h2(w0.x), u0,
                 fdot2f(h2(w0.y), u1,
                 fdot2f(h2(w0.z), u2, fdot2f(h2(w0.w), u3, 0.f))));
      float a1 = fdot2f(h2(w1.x), u0,
                 fdot2f(h2(w1.y), u1,
                 fdot2f(h2(w1.z), u2, fdot2f(h2(w1.w), u3, 0.f))));
      uh[e] = pkh2(a0, a1);
      ADV(i, dp)
    }
  }
  int jslot = t >> 4;           // 0..15
  int dbase = t % 80;           // D[k] = (dbase + 16k) % 80

  for (int it = 0; it < 3; ++it) {
    if (it > 0) {
      __syncthreads();   // b-update atomics complete
      if (t < 144) {
        const float* br = &blog[t * 10];
        float mx = br[0];
#pragma unroll
        for (int o = 1; o < 10; ++o) mx = fmaxf(mx, br[o]);
        float e[10];
        float sum = 0.f;
#pragma unroll
        for (int o = 0; o < 10; ++o) { e[o] = __expf(br[o] - mx); sum += e[o]; }
        float inv = 1.0f / sum;
#pragma unroll
        for (int o = 0; o < 10; ++o) cc[t * 10 + o] = e[o] * inv;
      }
    }
    __syncthreads();   // cc ready; spart free for reuse
    // ---- s partials: 5 local accumulators (dp has period 5 in e) ----
    {
      float aloc[5][2] = {{0.f,0.f},{0.f,0.f},{0.f,0.f},{0.f,0.f},{0.f,0.f}};
      int i = t / 80, dp = t - (t / 80) * 80;
      if (it == 0) {
#pragma unroll
        for (int e = 0; e < 45; ++e) {
          half2_t h = h2(uh[e]);
          aloc[e % 5][0] += (float)h[0];
          aloc[e % 5][1] += (float)h[1];
          ADV(i, dp)
        }
      } else {
#pragma unroll
        for (int e = 0; e < 45; ++e) {
          float c = cc[i * 10 + (dp >> 3)];
          half2_t h = h2(uh[e]);
          aloc[e % 5][0] += c * (float)h[0];
          aloc[e % 5][1] += c * (float)h[1];
          ADV(i, dp)
        }
      }
#pragma unroll
      for (int k = 0; k < 5; ++k) {
        int dpk = dbase + 16 * k;
        dpk -= (dpk >= 80) ? 80 : 0;
        spart[(dpk * 17 + jslot) * 2] = aloc[k][0];
        spart[(dpk * 17 + jslot) * 2 + 1] = aloc[k][1];
      }
    }
    __syncthreads();
    if (t < 160) {   // reduce 16 j-slots; ss[dp*2+c] == s[o][d]
      int dp = t >> 1, c = t & 1;
      float s = 0.f;
#pragma unroll
      for (int j = 0; j < 16; ++j) s += spart[(dp * 17 + j) * 2 + c];
      ss[t] = (it == 0) ? s * 0.1f : s;   // it==0: softmax of zeros = 0.1
    }
    __syncthreads();
    if (t < 10) {
      float sq = 0.f;
#pragma unroll
      for (int d = 0; d < 16; ++d) { float x = ss[t * 16 + d]; sq += x * x; }
      float coef = (sq / (1.0f + sq)) / sqrtf(sq + 1e-8f);
#pragma unroll
      for (int q = 0; q < 8; ++q) {
        float v0 = coef * ss[t * 16 + 2 * q];
        float v1 = coef * ss[t * 16 + 2 * q + 1];
        vv[t * 16 + 2 * q] = v0;
        vv[t * 16 + 2 * q + 1] = v1;
        vvh[t * 8 + q] = pkh2(v0, v1);
      }
      if (it == 2) out[b * 10 + t] = coef * sqrtf(sq);   // pred = ||v||
    }
    __syncthreads();
    if (it < 2) {   // b-update: 45 ds_add_f32 atomics (~8 adds/address)
      int i = t / 80, dp = t - (t / 80) * 80;
#pragma unroll
      for (int e = 0; e < 45; ++e) {
        int o = dp >> 3;
        float d = fdot2f(h2(uh[e]), h2(vvh[dp]), 0.f);
        atomicAdd(&blog[i * 10 + o], d);
        ADV(i, dp)
      }
    }
  }
  if (t < 160) out[B * 10 + b * 160 + t] = vv[t];
}

extern "C" void kernel_launch(void* const* d_in, const int* in_sizes, int n_in,
                              void* d_out, int out_size, void* d_ws, size_t ws_size,
                              hipStream_t stream) {
  const float* in = (const float*)d_in[0];
  const float* w1 = (const float*)d_in[1];
  const float* b1 = (const float*)d_in[2];
  const float* w2 = (const float*)d_in[3];
  const float* b2 = (const float*)d_in[4];
  const float* Wr = (const float*)d_in[5];
  float* out = (float*)d_out;
  int B = in_sizes[0] / 784;
  float* wsf = (float*)d_ws;

  float* u = wsf;                                       // [B][1152] f32
  _Float16* x1t = (_Float16*)(wsf + (size_t)B * 1152);  // B*6400 f16
  float* tail = wsf + (size_t)B * 1152 + (size_t)B * 3200;
  _Float16* wBg = (_Float16*)tail;                      // 41472 f16 = 20736 f
  unsigned int* wPr = (unsigned int*)(tail + 20736);    // 92160 dw

  packWB<<<162, 256, 0, stream>>>(w2, wBg);
  packWr<<<360, 256, 0, stream>>>(Wr, wPr);
  conv1_kernel<<<B, 320, 0, stream>>>(in, w1, b1, x1t);
  conv2_kernel<<<B / 8, 256, 0, stream>>>(x1t, wBg, b2, u);
  routing3_kernel<<<B, 256, 0, stream>>>(u, wPr, out, B);
}

// Round 10
// 449.608 us; speedup vs baseline: 1.3130x; 1.3130x over previous
//
#include <hip/hip_runtime.h>

// CapsNet forward.
// conv1 (fp32 compute) -> x1t f16 [B][ih=20][iw=20][ci=16]  (ci innermost)
// packWB: w2 -> MFMA B-fragments; conv2: mfma_32x32x16_f16 -> u [B][144][8] f32
// packWr: W_route -> f16 c-pairs
// routing3: 1 sample/block, 256 thr; u_hat in 45 VGPRs/thread (no LDS u_hat);
//           LDS ~26 KB. NO occupancy clamp (round 9's (256,4) caused a 1 GB
//           scratch spill: VGPR=64, FETCH 432 MB). Compiler picks ~110-140 VGPR.

typedef _Float16 half2_t __attribute__((ext_vector_type(2)));
typedef _Float16 f16x8 __attribute__((ext_vector_type(8)));
typedef float f32x16 __attribute__((ext_vector_type(16)));

static __device__ __forceinline__ float fdot2f(half2_t a, half2_t b, float c) {
#if __has_builtin(__builtin_amdgcn_fdot2)
  return __builtin_amdgcn_fdot2(a, b, c, false);
#else
  return c + (float)a[0] * (float)b[0] + (float)a[1] * (float)b[1];
#endif
}

static __device__ __forceinline__ half2_t h2(unsigned int u) {
  return __builtin_bit_cast(half2_t, u);
}

static __device__ __forceinline__ unsigned int pkh2(float a, float b) {
  half2_t h;
  h[0] = (_Float16)a;
  h[1] = (_Float16)b;
  return __builtin_bit_cast(unsigned int, h);
}

static __device__ __forceinline__ f32x16 zero16() {
  f32x16 z = {0.f, 0.f, 0.f, 0.f, 0.f, 0.f, 0.f, 0.f,
              0.f, 0.f, 0.f, 0.f, 0.f, 0.f, 0.f, 0.f};
  return z;
}

// w2[co][ci][kh][kw] f32 -> wBg[((kh*9+kw)*64 + lane)*8 + j] f16
__global__ __launch_bounds__(256) void packWB(
    const float* __restrict__ w2, _Float16* __restrict__ wBg) {
  int idx = blockIdx.x * 256 + threadIdx.x;
  if (idx >= 41472) return;
  int j = idx & 7;
  int lane = (idx >> 3) & 63;
  int step = idx >> 9;
  int kh = step / 9, kw = step - kh * 9;
  int co = lane & 31, ci = (lane >> 5) * 8 + j;
  wBg[idx] = (_Float16)w2[(co * 16 + ci) * 81 + kh * 9 + kw];
}

// W_route [144][10][16][8] f32 -> wPr [(i*10+o)*16+d][4] f16 c-pairs
__global__ __launch_bounds__(256) void packWr(
    const float* __restrict__ W, unsigned int* __restrict__ wPr) {
  int idx = blockIdx.x * 256 + threadIdx.x;   // 92160 dwords
  if (idx >= 92160) return;
  int cp = idx & 3;
  int row = idx >> 2;
  const float* src = W + (size_t)row * 8 + cp * 2;
  wPr[idx] = pkh2(src[0], src[1]);
}

__global__ __launch_bounds__(320) void conv1_kernel(
    const float* __restrict__ in, const float* __restrict__ w,
    const float* __restrict__ bias, _Float16* __restrict__ x1t) {
  __shared__ __align__(16) float sIn[784];      // 28x28
  __shared__ float sW[1296];                    // 16x81
  __shared__ __align__(16) _Float16 sOut[6400]; // [ih][iw][ci]
  int b = blockIdx.x, t = threadIdx.x;
  const float* inb = in + b * 784;
  for (int i = t; i < 784; i += 320) sIn[i] = inb[i];
  for (int i = t; i < 1296; i += 320) sW[i] = w[i];
  __syncthreads();
  int co = t / 20, oh = t % 20;   // 16*20 = 320 work items
  float bv = bias[co];
  float acc[20];
#pragma unroll
  for (int j = 0; j < 20; ++j) acc[j] = bv;
#pragma unroll
  for (int kh = 0; kh < 9; ++kh) {
    float r[28];
    const float4* row = (const float4*)&sIn[(oh + kh) * 28];
#pragma unroll
    for (int q = 0; q < 7; ++q) {
      float4 v = row[q];
      r[q * 4 + 0] = v.x; r[q * 4 + 1] = v.y; r[q * 4 + 2] = v.z; r[q * 4 + 3] = v.w;
    }
    const float* wr = &sW[co * 81 + kh * 9];
#pragma unroll
    for (int kw = 0; kw < 9; ++kw) {
      float wv = wr[kw];
#pragma unroll
      for (int j = 0; j < 20; ++j) acc[j] += wv * r[kw + j];
    }
  }
#pragma unroll
  for (int j = 0; j < 20; ++j) sOut[(oh * 20 + j) * 16 + co] = (_Float16)acc[j];
  __syncthreads();
  const unsigned int* s4 = (const unsigned int*)sOut;
  unsigned int* g4 = (unsigned int*)(x1t + (size_t)b * 6400);
  for (int i = t; i < 3200; i += 320) g4[i] = s4[i];
}

// conv2 MFMA: block = 8 samples (288 rows = 9 M-tiles of 32), 4 waves.
__global__ __launch_bounds__(256) void conv2_kernel(
    const _Float16* __restrict__ x1t, const _Float16* __restrict__ wBg,
    const float* __restrict__ bias, float* __restrict__ u) {
  __shared__ __align__(16) _Float16 sX[51200];  // 8 x [400][16]
  __shared__ __align__(16) _Float16 sB[4608];   // [kw 9][lane 64][8]
  int t = threadIdx.x;
  int bbase = blockIdx.x * 8;
  {
    const uint4* g = (const uint4*)(x1t + (size_t)bbase * 6400);
    uint4* s = (uint4*)sX;
#pragma unroll
    for (int i = 0; i < 25; ++i) s[t + i * 256] = g[t + i * 256];
  }
  int wv = t >> 6, lane = t & 63;
  int l31 = lane & 31, half = lane >> 5;
  int tbase0 = 0, tbase1 = 0, tbase2 = 0;
  {
    int r = wv * 32 + l31;
    int s = r / 36, pos = r - s * 36, oh = pos / 6, ow = pos - oh * 6;
    tbase0 = s * 6400 + (oh * 40 + ow * 2) * 16 + half * 8;
    r += 128;
    s = r / 36; pos = r - s * 36; oh = pos / 6; ow = pos - oh * 6;
    tbase1 = s * 6400 + (oh * 40 + ow * 2) * 16 + half * 8;
    if (wv == 0) {
      r = 256 + l31;
      s = r / 36; pos = r - s * 36; oh = pos / 6; ow = pos - oh * 6;
      tbase2 = s * 6400 + (oh * 40 + ow * 2) * 16 + half * 8;
    }
  }
  f32x16 acc0 = zero16(), acc1 = zero16(), acc2 = zero16();

  for (int kh = 0; kh < 9; ++kh) {
    __syncthreads();
    {
      const unsigned int* g = (const unsigned int*)(wBg + kh * 4608);
      unsigned int* s = (unsigned int*)sB;
#pragma unroll
      for (int i = 0; i < 9; ++i) s[t + i * 256] = g[t + i * 256];
    }
    __syncthreads();
    int abase = kh * 320;
#pragma unroll
    for (int kw = 0; kw < 9; ++kw) {
      f16x8 bf = *(const f16x8*)(sB + kw * 512 + lane * 8);
      f16x8 a0 = *(const f16x8*)(sX + tbase0 + abase + kw * 16);
      acc0 = __builtin_amdgcn_mfma_f32_32x32x16_f16(a0, bf, acc0, 0, 0, 0);
      f16x8 a1 = *(const f16x8*)(sX + tbase1 + abase + kw * 16);
      acc1 = __builtin_amdgcn_mfma_f32_32x32x16_f16(a1, bf, acc1, 0, 0, 0);
      if (wv == 0) {
        f16x8 a2 = *(const f16x8*)(sX + tbase2 + abase + kw * 16);
        acc2 = __builtin_amdgcn_mfma_f32_32x32x16_f16(a2, bf, acc2, 0, 0, 0);
      }
    }
  }
  float bv = bias[l31];
  int c8 = l31 >> 2;
  int ibco = (l31 & 3) * 36;
#pragma unroll
  for (int reg = 0; reg < 16; ++reg) {
    int rbase = (reg & 3) + 8 * (reg >> 2) + 4 * half;
    {
      int r = wv * 32 + rbase;
      int s = r / 36, pos = r - s * 36;
      u[(size_t)(bbase + s) * 1152 + (ibco + pos) * 8 + c8] = acc0[reg] + bv;
    }
    {
      int r = wv * 32 + 128 + rbase;
      int s = r / 36, pos = r - s * 36;
      u[(size_t)(bbase + s) * 1152 + (ibco + pos) * 8 + c8] = acc1[reg] + bv;
    }
    if (wv == 0) {
      int r = 256 + rbase;
      int s = r / 36, pos = r - s * 36;
      u[(size_t)(bbase + s) * 1152 + (ibco + pos) * 8 + c8] = acc2[reg] + bv;
    }
  }
}

// routing3: block = 1 sample, 256 threads. u_hat entirely in registers:
// thread t owns idx = e*256+t, e<45 (i = idx/80, dp = idx%80; dp cycles over
// exactly 5 values since 256 = 3*80+16). LDS ~26 KB. No occupancy clamp.
#define ADV(i, dp) { dp += 16; int ov = (dp >= 80) ? 1 : 0; dp -= ov * 80; i += 3 + ov; }
__global__ __launch_bounds__(256) void routing3_kernel(
    const float* __restrict__ u, const unsigned int* __restrict__ wPr,
    float* __restrict__ out, int B) {
  __shared__ unsigned int ush[576];   // u f16 c-pairs [i][4]
  __shared__ float blog[1440];        // b [144][10] (atomically updated)
  __shared__ float cc[1440];          // c [144][10]
  __shared__ float spart[2720];       // [dp 80][j 17pad][2] partial s
  __shared__ float ss[160];           // s (dp*2+c ordering == [o][d])
  __shared__ float vv[160];           // v [10][16]
  __shared__ unsigned int vvh[80];    // v f16 d-pairs
  int b = blockIdx.x, t = threadIdx.x;
  const float* ub = u + (size_t)b * 1152;
  for (int j = t; j < 576; j += 256) {
    float2 p = *(const float2*)(ub + j * 2);
    ush[j] = pkh2(p.x, p.y);
  }
  for (int j = t; j < 1440; j += 256) blog[j] = 0.f;
  __syncthreads();

  // ---- u_hat into registers: uh[e] = f16 pair (d=2dd, 2dd+1) of (i, o) ----
  unsigned int uh[45];
  {
    const uint4* W4 = (const uint4*)wPr;   // rows [i*160 + o*16 + d] of 8 f16
    int i = t / 80, dp = t - (t / 80) * 80;
#pragma unroll
    for (int e = 0; e < 45; ++e) {
      int row = i * 160 + (dp >> 3) * 16 + (dp & 7) * 2;
      uint4 w0 = W4[row], w1 = W4[row + 1];
      const uint2* up = (const uint2*)&ush[i * 4];
      uint2 ua = up[0], ub2 = up[1];
      half2_t u0 = h2(ua.x), u1 = h2(ua.y), u2 = h2(ub2.x), u3 = h2(ub2.y);
      float a0 = fdot2f(h2(w0.x), u0,
                 fdot2f(h2(w0.y), u1,
                 fdot2f(h2(w0.z), u2, fdot2f(h2(w0.w), u3, 0.f))));
      float a1 = fdot2f(h2(w1.x), u0,
                 fdot2f(h2(w1.y), u1,
                 fdot2f(h2(w1.z), u2, fdot2f(h2(w1.w), u3, 0.f))));
      uh[e] = pkh2(a0, a1);
      ADV(i, dp)
    }
  }
  int jslot = t >> 4;           // 0..15
  int dbase = t % 80;           // D[k] = (dbase + 16k) % 80

  for (int it = 0; it < 3; ++it) {
    if (it > 0) {
      __syncthreads();   // b-update atomics complete
      if (t < 144) {
        const float* br = &blog[t * 10];
        float mx = br[0];
#pragma unroll
        for (int o = 1; o < 10; ++o) mx = fmaxf(mx, br[o]);
        float e[10];
        float sum = 0.f;
#pragma unroll
        for (int o = 0; o < 10; ++o) { e[o] = __expf(br[o] - mx); sum += e[o]; }
        float inv = 1.0f / sum;
#pragma unroll
        for (int o = 0; o < 10; ++o) cc[t * 10 + o] = e[o] * inv;
      }
    }
    __syncthreads();   // cc ready; spart free for reuse
    // ---- s partials: 5 local accumulators (dp has period 5 in e) ----
    {
      float aloc[5][2] = {{0.f,0.f},{0.f,0.f},{0.f,0.f},{0.f,0.f},{0.f,0.f}};
      int i = t / 80, dp = t - (t / 80) * 80;
      if (it == 0) {
#pragma unroll
        for (int e = 0; e < 45; ++e) {
          half2_t h = h2(uh[e]);
          aloc[e % 5][0] += (float)h[0];
          aloc[e % 5][1] += (float)h[1];
          ADV(i, dp)
        }
      } else {
#pragma unroll
        for (int e = 0; e < 45; ++e) {
          float c = cc[i * 10 + (dp >> 3)];
          half2_t h = h2(uh[e]);
          aloc[e % 5][0] += c * (float)h[0];
          aloc[e % 5][1] += c * (float)h[1];
          ADV(i, dp)
        }
      }
#pragma unroll
      for (int k = 0; k < 5; ++k) {
        int dpk = dbase + 16 * k;
        dpk -= (dpk >= 80) ? 80 : 0;
        spart[(dpk * 17 + jslot) * 2] = aloc[k][0];
        spart[(dpk * 17 + jslot) * 2 + 1] = aloc[k][1];
      }
    }
    __syncthreads();
    if (t < 160) {   // reduce 16 j-slots; ss[dp*2+c] == s[o][d]
      int dp = t >> 1, c = t & 1;
      float s = 0.f;
#pragma unroll
      for (int j = 0; j < 16; ++j) s += spart[(dp * 17 + j) * 2 + c];
      ss[t] = (it == 0) ? s * 0.1f : s;   // it==0: softmax of zeros = 0.1
    }
    __syncthreads();
    if (t < 10) {
      float sq = 0.f;
#pragma unroll
      for (int d = 0; d < 16; ++d) { float x = ss[t * 16 + d]; sq += x * x; }
      float coef = (sq / (1.0f + sq)) / sqrtf(sq + 1e-8f);
#pragma unroll
      for (int q = 0; q < 8; ++q) {
        float v0 = coef * ss[t * 16 + 2 * q];
        float v1 = coef * ss[t * 16 + 2 * q + 1];
        vv[t * 16 + 2 * q] = v0;
        vv[t * 16 + 2 * q + 1] = v1;
        vvh[t * 8 + q] = pkh2(v0, v1);
      }
      if (it == 2) out[b * 10 + t] = coef * sqrtf(sq);   // pred = ||v||
    }
    __syncthreads();
    if (it < 2) {   // b-update: 45 ds_add_f32 atomics (~8 adds/address)
      int i = t / 80, dp = t - (t / 80) * 80;
#pragma unroll
      for (int e = 0; e < 45; ++e) {
        int o = dp >> 3;
        float d = fdot2f(h2(uh[e]), h2(vvh[dp]), 0.f);
        atomicAdd(&blog[i * 10 + o], d);
        ADV(i, dp)
      }
    }
  }
  if (t < 160) out[B * 10 + b * 160 + t] = vv[t];
}

extern "C" void kernel_launch(void* const* d_in, const int* in_sizes, int n_in,
                              void* d_out, int out_size, void* d_ws, size_t ws_size,
                              hipStream_t stream) {
  const float* in = (const float*)d_in[0];
  const float* w1 = (const float*)d_in[1];
  const float* b1 = (const float*)d_in[2];
  const float* w2 = (const float*)d_in[3];
  const float* b2 = (const float*)d_in[4];
  const float* Wr = (const float*)d_in[5];
  float* out = (float*)d_out;
  int B = in_sizes[0] / 784;
  float* wsf = (float*)d_ws;

  float* u = wsf;                                       // [B][1152] f32
  _Float16* x1t = (_Float16*)(wsf + (size_t)B * 1152);  // B*6400 f16
  float* tail = wsf + (size_t)B * 1152 + (size_t)B * 3200;
  _Float16* wBg = (_Float16*)tail;                      // 41472 f16 = 20736 f
  unsigned int* wPr = (unsigned int*)(tail + 20736);    // 92160 dw

  packWB<<<162, 256, 0, stream>>>(w2, wBg);
  packWr<<<360, 256, 0, stream>>>(Wr, wPr);
  conv1_kernel<<<B, 320, 0, stream>>>(in, w1, b1, x1t);
  conv2_kernel<<<B / 8, 256, 0, stream>>>(x1t, wBg, b2, u);
  routing3_kernel<<<B, 256, 0, stream>>>(u, wPr, out, B);
}

// Round 11
// 139.822 us; speedup vs baseline: 4.2220x; 3.2156x over previous
//
#include <hip/hip_runtime.h>

// CapsNet forward.
// packAll: w2 -> MFMA B-fragments + W_route -> f16 c-pairs (one kernel)
// conv1: f16 dot2 (even/odd pair staging) -> x1t f16 [B][20][20][16]
// conv2: mfma_32x32x16_f16 -> u [B][144][8] f32   (round-8 proven)
// routing2: 2 samples/block, 1024 thr (16 waves/CU), u_hat f16 in LDS,
//           W streamed from L2 once per block with 2-deep prefetch.

typedef _Float16 half2_t __attribute__((ext_vector_type(2)));
typedef _Float16 f16x8 __attribute__((ext_vector_type(8)));
typedef float f32x16 __attribute__((ext_vector_type(16)));

static __device__ __forceinline__ float fdot2f(half2_t a, half2_t b, float c) {
#if __has_builtin(__builtin_amdgcn_fdot2)
  return __builtin_amdgcn_fdot2(a, b, c, false);
#else
  return c + (float)a[0] * (float)b[0] + (float)a[1] * (float)b[1];
#endif
}

static __device__ __forceinline__ half2_t h2(unsigned int u) {
  return __builtin_bit_cast(half2_t, u);
}

static __device__ __forceinline__ unsigned int pkh2(float a, float b) {
  half2_t h;
  h[0] = (_Float16)a;
  h[1] = (_Float16)b;
  return __builtin_bit_cast(unsigned int, h);
}

static __device__ __forceinline__ f32x16 zero16() {
  f32x16 z = {0.f, 0.f, 0.f, 0.f, 0.f, 0.f, 0.f, 0.f,
              0.f, 0.f, 0.f, 0.f, 0.f, 0.f, 0.f, 0.f};
  return z;
}

// Fused packs. idx < 92160: W_route -> wPr f16 c-pairs.
//              idx < 41472: w2 -> wBg MFMA B-fragments.
__global__ __launch_bounds__(256) void packAll(
    const float* __restrict__ w2, const float* __restrict__ Wr,
    _Float16* __restrict__ wBg, unsigned int* __restrict__ wPr) {
  int idx = blockIdx.x * 256 + threadIdx.x;
  if (idx < 92160) {
    int cp = idx & 3;
    int row = idx >> 2;
    const float* src = Wr + (size_t)row * 8 + cp * 2;
    wPr[idx] = pkh2(src[0], src[1]);
  }
  if (idx < 41472) {
    int j = idx & 7;
    int lane = (idx >> 3) & 63;
    int step = idx >> 9;
    int kh = step / 9, kw = step - kh * 9;
    int co = lane & 31, ci = (lane >> 5) * 8 + j;
    wBg[idx] = (_Float16)w2[(co * 16 + ci) * 81 + kh * 9 + kw];
  }
}

// conv1 via f16 dot2: stage input as even/odd f16 pairs + weight kw-pairs.
__global__ __launch_bounds__(320) void conv1_kernel(
    const float* __restrict__ in, const float* __restrict__ w,
    const float* __restrict__ bias, _Float16* __restrict__ x1t) {
  __shared__ __align__(16) float sIn[784];        // 28x28 f32
  __shared__ __align__(16) unsigned int sPE[448]; // [28][16] even pairs
  __shared__ __align__(16) unsigned int sPO[448]; // [28][16] odd pairs
  __shared__ unsigned int sWP[720];               // [co][kh][5] w kw-pairs
  __shared__ __align__(16) _Float16 sOut[6400];   // [ih][iw][ci]
  int b = blockIdx.x, t = threadIdx.x;
  const float* inb = in + b * 784;
  for (int i = t; i < 784; i += 320) sIn[i] = inb[i];
  for (int i = t; i < 720; i += 320) {
    int co = i / 45, r = i % 45, kh = r / 5, p = r % 5;
    int k0 = 2 * p, k1 = 2 * p + 1;
    float a = w[co * 81 + kh * 9 + k0];
    float bb = (k1 < 9) ? w[co * 81 + kh * 9 + k1] : 0.f;
    sWP[i] = pkh2(a, bb);
  }
  __syncthreads();
  for (int j = t; j < 896; j += 320) {
    int row = j >> 5, col = j & 31;
    int which = col >> 4, p = col & 15;
    const float* rp = &sIn[row * 28];
    int i0 = 2 * p + which, i1 = i0 + 1;
    float a = (i0 < 28) ? rp[i0] : 0.f;
    float bb = (i1 < 28) ? rp[i1] : 0.f;
    unsigned int pk = pkh2(a, bb);
    if (which == 0) sPE[row * 16 + p] = pk; else sPO[row * 16 + p] = pk;
  }
  __syncthreads();
  int co = t / 20, oh = t % 20;   // 16*20 = 320 work items
  float bv = bias[co];
  float acc[20];
#pragma unroll
  for (int j = 0; j < 20; ++j) acc[j] = bv;
#pragma unroll
  for (int kh = 0; kh < 9; ++kh) {
    int row = oh + kh;
    half2_t pe[16], po[16];
    {
      const uint4* p4 = (const uint4*)&sPE[row * 16];
      const uint4* o4 = (const uint4*)&sPO[row * 16];
#pragma unroll
      for (int q = 0; q < 4; ++q) {
        uint4 e = p4[q], o = o4[q];
        pe[q * 4 + 0] = h2(e.x); pe[q * 4 + 1] = h2(e.y);
        pe[q * 4 + 2] = h2(e.z); pe[q * 4 + 3] = h2(e.w);
        po[q * 4 + 0] = h2(o.x); po[q * 4 + 1] = h2(o.y);
        po[q * 4 + 2] = h2(o.z); po[q * 4 + 3] = h2(o.w);
      }
    }
    half2_t wp[5];
#pragma unroll
    for (int p = 0; p < 5; ++p) wp[p] = h2(sWP[co * 45 + kh * 5 + p]);
#pragma unroll
    for (int j = 0; j < 20; ++j) {
      int jj = j >> 1;
      float a = acc[j];
      if ((j & 1) == 0) {
#pragma unroll
        for (int p = 0; p < 5; ++p) a = fdot2f(wp[p], pe[jj + p], a);
      } else {
#pragma unroll
        for (int p = 0; p < 5; ++p) a = fdot2f(wp[p], po[jj + p], a);
      }
      acc[j] = a;
    }
  }
#pragma unroll
  for (int j = 0; j < 20; ++j) sOut[(oh * 20 + j) * 16 + co] = (_Float16)acc[j];
  __syncthreads();
  const unsigned int* s4 = (const unsigned int*)sOut;
  unsigned int* g4 = (unsigned int*)(x1t + (size_t)b * 6400);
  for (int i = t; i < 3200; i += 320) g4[i] = s4[i];
}

// conv2 MFMA: block = 8 samples (288 rows = 9 M-tiles of 32), 4 waves.
__global__ __launch_bounds__(256) void conv2_kernel(
    const _Float16* __restrict__ x1t, const _Float16* __restrict__ wBg,
    const float* __restrict__ bias, float* __restrict__ u) {
  __shared__ __align__(16) _Float16 sX[51200];  // 8 x [400][16]
  __shared__ __align__(16) _Float16 sB[4608];   // [kw 9][lane 64][8]
  int t = threadIdx.x;
  int bbase = blockIdx.x * 8;
  {
    const uint4* g = (const uint4*)(x1t + (size_t)bbase * 6400);
    uint4* s = (uint4*)sX;
#pragma unroll
    for (int i = 0; i < 25; ++i) s[t + i * 256] = g[t + i * 256];
  }
  int wv = t >> 6, lane = t & 63;
  int l31 = lane & 31, half = lane >> 5;
  int tbase0 = 0, tbase1 = 0, tbase2 = 0;
  {
    int r = wv * 32 + l31;
    int s = r / 36, pos = r - s * 36, oh = pos / 6, ow = pos - oh * 6;
    tbase0 = s * 6400 + (oh * 40 + ow * 2) * 16 + half * 8;
    r += 128;
    s = r / 36; pos = r - s * 36; oh = pos / 6; ow = pos - oh * 6;
    tbase1 = s * 6400 + (oh * 40 + ow * 2) * 16 + half * 8;
    if (wv == 0) {
      r = 256 + l31;
      s = r / 36; pos = r - s * 36; oh = pos / 6; ow = pos - oh * 6;
      tbase2 = s * 6400 + (oh * 40 + ow * 2) * 16 + half * 8;
    }
  }
  f32x16 acc0 = zero16(), acc1 = zero16(), acc2 = zero16();

  for (int kh = 0; kh < 9; ++kh) {
    __syncthreads();
    {
      const unsigned int* g = (const unsigned int*)(wBg + kh * 4608);
      unsigned int* s = (unsigned int*)sB;
#pragma unroll
      for (int i = 0; i < 9; ++i) s[t + i * 256] = g[t + i * 256];
    }
    __syncthreads();
    int abase = kh * 320;
#pragma unroll
    for (int kw = 0; kw < 9; ++kw) {
      f16x8 bf = *(const f16x8*)(sB + kw * 512 + lane * 8);
      f16x8 a0 = *(const f16x8*)(sX + tbase0 + abase + kw * 16);
      acc0 = __builtin_amdgcn_mfma_f32_32x32x16_f16(a0, bf, acc0, 0, 0, 0);
      f16x8 a1 = *(const f16x8*)(sX + tbase1 + abase + kw * 16);
      acc1 = __builtin_amdgcn_mfma_f32_32x32x16_f16(a1, bf, acc1, 0, 0, 0);
      if (wv == 0) {
        f16x8 a2 = *(const f16x8*)(sX + tbase2 + abase + kw * 16);
        acc2 = __builtin_amdgcn_mfma_f32_32x32x16_f16(a2, bf, acc2, 0, 0, 0);
      }
    }
  }
  float bv = bias[l31];
  int c8 = l31 >> 2;
  int ibco = (l31 & 3) * 36;
#pragma unroll
  for (int reg = 0; reg < 16; ++reg) {
    int rbase = (reg & 3) + 8 * (reg >> 2) + 4 * half;
    {
      int r = wv * 32 + rbase;
      int s = r / 36, pos = r - s * 36;
      u[(size_t)(bbase + s) * 1152 + (ibco + pos) * 8 + c8] = acc0[reg] + bv;
    }
    {
      int r = wv * 32 + 128 + rbase;
      int s = r / 36, pos = r - s * 36;
      u[(size_t)(bbase + s) * 1152 + (ibco + pos) * 8 + c8] = acc1[reg] + bv;
    }
    if (wv == 0) {
      int r = 256 + rbase;
      int s = r / 36, pos = r - s * 36;
      u[(size_t)(bbase + s) * 1152 + (ibco + pos) * 8 + c8] = acc2[reg] + bv;
    }
  }
}

// routing2: block = 2 samples, 1024 threads (16 waves/CU). u_hat f16 in LDS.
// W_route f16 streamed from L2 once per block with 2-deep prefetch.
__global__ __launch_bounds__(1024) void routing2_kernel(
    const float* __restrict__ u, const unsigned int* __restrict__ wPr,
    float* __restrict__ out, int B) {
  __shared__ unsigned int uhh[2][11808];   // [sl][i*82+dp] f16 d-pairs (80 used)
  __shared__ unsigned int ush[2][576];     // u f16 c-pairs [i][4]
  __shared__ float blog[2][1440];
  __shared__ float cc[2][1440];
  __shared__ float spart[2][960];          // [sl][ch 6][160]
  __shared__ float ss[2][160];
  __shared__ float vv[2][160];
  __shared__ unsigned int vvh[2][80];
  int b0 = blockIdx.x * 2, t = threadIdx.x;
  for (int j = t; j < 1152; j += 1024) {
    int sl2 = j / 576, k = j - sl2 * 576;
    float2 p = *(const float2*)(u + (size_t)(b0 + sl2) * 1152 + k * 2);
    ush[sl2][k] = pkh2(p.x, p.y);
  }
  for (int j = t; j < 2880; j += 1024) blog[j / 1440][j % 1440] = 0.f;
  __syncthreads();

  // ---- u_hat with 2-deep W prefetch ----
  {
    const uint4* W4 = (const uint4*)wPr;   // rows [i*160+o*16+d] of 8 f16
    int idx = t;
    bool valid = idx < 11520;
    int i_ = 0, dp_ = 0;
    uint4 w0a, w1a;
    if (valid) {
      i_ = idx / 80; dp_ = idx - i_ * 80;
      int row = i_ * 160 + (dp_ >> 3) * 16 + (dp_ & 7) * 2;
      w0a = W4[row]; w1a = W4[row + 1];
    }
    while (valid) {
      int nidx = idx + 1024;
      bool nvalid = nidx < 11520;
      int ni = 0, ndp = 0;
      uint4 w0b, w1b;
      if (nvalid) {
        ni = nidx / 80; ndp = nidx - ni * 80;
        int nrow = ni * 160 + (ndp >> 3) * 16 + (ndp & 7) * 2;
        w0b = W4[nrow]; w1b = W4[nrow + 1];
      }
#pragma unroll
      for (int sl2 = 0; sl2 < 2; ++sl2) {
        const uint2* up = (const uint2*)&ush[sl2][i_ * 4];
        uint2 ua = up[0], ub = up[1];
        half2_t u0 = h2(ua.x), u1 = h2(ua.y), u2 = h2(ub.x), u3 = h2(ub.y);
        float a0 = fdot2f(h2(w0a.x), u0,
                   fdot2f(h2(w0a.y), u1,
                   fdot2f(h2(w0a.z), u2, fdot2f(h2(w0a.w), u3, 0.f))));
        float a1 = fdot2f(h2(w1a.x), u0,
                   fdot2f(h2(w1a.y), u1,
                   fdot2f(h2(w1a.z), u2, fdot2f(h2(w1a.w), u3, 0.f))));
        uhh[sl2][i_ * 82 + dp_] = pkh2(a0, a1);
      }
      idx = nidx; i_ = ni; dp_ = ndp;
      w0a = w0b; w1a = w1b;
      valid = nvalid;
    }
  }
  __syncthreads();

  int sl = t >> 9, tl = t & 511;
  for (int it = 0; it < 3; ++it) {
    if (it > 0) {
      if (tl < 144) {
        const float* br = &blog[sl][tl * 10];
        float mx = br[0];
#pragma unroll
        for (int o = 1; o < 10; ++o) mx = fmaxf(mx, br[o]);
        float e[10];
        float sum = 0.f;
#pragma unroll
        for (int o = 0; o < 10; ++o) { e[o] = __expf(br[o] - mx); sum += e[o]; }
        float inv = 1.0f / sum;
#pragma unroll
        for (int o = 0; o < 10; ++o) cc[sl][tl * 10 + o] = e[o] * inv;
      }
      __syncthreads();
    }
    // s partials: per sample, 480 lanes = 6 i-chunks x 80 d-pairs
    if (tl < 480) {
      int ch = tl / 80, dp = tl - ch * 80;
      int o = dp >> 3;
      float a0 = 0.f, a1 = 0.f;
      int i0 = ch * 24;
      if (it == 0) {
        for (int i = i0; i < i0 + 24; ++i) {
          half2_t h = h2(uhh[sl][i * 82 + dp]);
          a0 += (float)h[0]; a1 += (float)h[1];
        }
      } else {
        for (int i = i0; i < i0 + 24; ++i) {
          float c = cc[sl][i * 10 + o];
          half2_t h = h2(uhh[sl][i * 82 + dp]);
          a0 += c * (float)h[0]; a1 += c * (float)h[1];
        }
      }
      spart[sl][ch * 160 + dp * 2] = a0;
      spart[sl][ch * 160 + dp * 2 + 1] = a1;
    }
    __syncthreads();
    if (tl < 160) {
      float s = 0.f;
#pragma unroll
      for (int ch = 0; ch < 6; ++ch) s += spart[sl][ch * 160 + tl];
      ss[sl][tl] = (it == 0) ? s * 0.1f : s;   // it==0: softmax of zeros = 0.1
    }
    __syncthreads();
    if (tl < 10) {
      float sq = 0.f;
#pragma unroll
      for (int d = 0; d < 16; ++d) { float x = ss[sl][tl * 16 + d]; sq += x * x; }
      float coef = (sq / (1.0f + sq)) / sqrtf(sq + 1e-8f);
#pragma unroll
      for (int q = 0; q < 8; ++q) {
        float v0 = coef * ss[sl][tl * 16 + 2 * q];
        float v1 = coef * ss[sl][tl * 16 + 2 * q + 1];
        vv[sl][tl * 16 + 2 * q] = v0;
        vv[sl][tl * 16 + 2 * q + 1] = v1;
        vvh[sl][tl * 8 + q] = pkh2(v0, v1);
      }
      if (it == 2) out[(b0 + sl) * 10 + tl] = coef * sqrtf(sq);   // pred
    }
    __syncthreads();
    if (it < 2) {
      for (int idx = t; idx < 2880; idx += 1024) {
        int s2 = idx / 1440, r = idx - s2 * 1440;
        int i = r / 10, o = r - i * 10;
        const uint2* uhp = (const uint2*)&uhh[s2][i * 82 + o * 8];
        const uint2* vp = (const uint2*)&vvh[s2][o * 8];
        float dot = 0.f;
#pragma unroll
        for (int q = 0; q < 4; ++q) {
          uint2 A = uhp[q], V = vp[q];
          dot = fdot2f(h2(A.x), h2(V.x), fdot2f(h2(A.y), h2(V.y), dot));
        }
        blog[s2][r] += dot;
      }
      __syncthreads();
    }
  }
  if (tl < 160) out[B * 10 + (b0 + sl) * 160 + tl] = vv[sl][tl];
}

extern "C" void kernel_launch(void* const* d_in, const int* in_sizes, int n_in,
                              void* d_out, int out_size, void* d_ws, size_t ws_size,
                              hipStream_t stream) {
  const float* in = (const float*)d_in[0];
  const float* w1 = (const float*)d_in[1];
  const float* b1 = (const float*)d_in[2];
  const float* w2 = (const float*)d_in[3];
  const float* b2 = (const float*)d_in[4];
  const float* Wr = (const float*)d_in[5];
  float* out = (float*)d_out;
  int B = in_sizes[0] / 784;
  float* wsf = (float*)d_ws;

  float* u = wsf;                                       // [B][1152] f32
  _Float16* x1t = (_Float16*)(wsf + (size_t)B * 1152);  // B*6400 f16
  float* tail = wsf + (size_t)B * 1152 + (size_t)B * 3200;
  _Float16* wBg = (_Float16*)tail;                      // 41472 f16 = 20736 f
  unsigned int* wPr = (unsigned int*)(tail + 20736);    // 92160 dw

  packAll<<<360, 256, 0, stream>>>(w2, Wr, wBg, wPr);
  conv1_kernel<<<B, 320, 0, stream>>>(in, w1, b1, x1t);
  conv2_kernel<<<B / 8, 256, 0, stream>>>(x1t, wBg, b2, u);
  routing2_kernel<<<B / 2, 1024, 0, stream>>>(u, wPr, out, B);
}